// Round 1
// baseline (730.758 us; speedup 1.0000x reference)
//
#include <hip/hip_runtime.h>

#define P_    4
#define K_    2048
#define D_    128
#define B_    16
#define HW_   784
#define N_    (B_ * HW_)          // 12544
#define C_    512

#define OUT0_SZ   (B_ * C_ * HW_) // 6422528
#define QLOSS_OFF OUT0_SZ
#define OUT2_OFF  (OUT0_SZ + 1)

typedef short  short8 __attribute__((ext_vector_type(8)));
typedef float  f32x4  __attribute__((ext_vector_type(4)));

__device__ __forceinline__ short f2bf(float x) {
    union { float f; unsigned u; } a; a.f = x;
    unsigned r = a.u + 0x7FFF + ((a.u >> 16) & 1);   // RNE
    return (short)(r >> 16);
}

// ---------------- prep: codebook -> bf16 + squared norms ----------------
__global__ __launch_bounds__(256) void vq_prep(const float* __restrict__ cb,
                                               short* __restrict__ cbb,
                                               float* __restrict__ cnorm) {
    int wave = threadIdx.x >> 6;
    int lane = threadIdx.x & 63;
    int row  = blockIdx.x * 4 + wave;            // 0 .. P_*K_-1
    const float* src = cb + (size_t)row * D_;
    float2 v = *(const float2*)(src + lane * 2);
    cbb[(size_t)row * D_ + lane * 2 + 0] = f2bf(v.x);
    cbb[(size_t)row * D_ + lane * 2 + 1] = f2bf(v.y);
    float s = v.x * v.x + v.y * v.y;
    #pragma unroll
    for (int m = 1; m < 64; m <<= 1) s += __shfl_xor(s, m, 64);
    if (lane == 0) cnorm[row] = s;
}

// ---------------- main: GEMM + fused softmax/argmax ----------------
// block = 256 thr (4 waves), handles one p and 16 n-rows, full K=2048 cols.
// wave w owns cols [w*512, w*512+512).
__global__ __launch_bounds__(256, 2) void vq_main(const float* __restrict__ z,
                                                  const short* __restrict__ cbb,
                                                  const float* __restrict__ cnorm,
                                                  int*   __restrict__ idx_out,
                                                  float* __restrict__ out2) {
    __shared__ short As[16][136];        // [n-row][k], +8 pad
    __shared__ float wsum[4][16];
    __shared__ float wmax[4][16];
    __shared__ int   wmidx[4][16];

    const int bx  = blockIdx.x;
    const int p   = bx / (N_ / 16);      // 784 tiles per p
    const int nt  = bx % (N_ / 16);
    const int b   = nt / 49;             // HW_=784 = 49*16, tiles never cross b
    const int hw0 = (nt % 49) * 16;
    const int n0  = nt * 16;             // == b*784 + hw0

    // --- stage A tile (16 rows x 128 k) as bf16, transposed, in LDS ---
    {
        int t    = threadIdx.x;
        int k    = t >> 1;
        int half = t & 1;
        const float* src = z + ((size_t)b * C_ + p * D_ + k) * HW_ + hw0 + half * 8;
        float4 v0 = *(const float4*)src;
        float4 v1 = *(const float4*)(src + 4);
        int r0 = half * 8;
        As[r0 + 0][k] = f2bf(v0.x);  As[r0 + 1][k] = f2bf(v0.y);
        As[r0 + 2][k] = f2bf(v0.z);  As[r0 + 3][k] = f2bf(v0.w);
        As[r0 + 4][k] = f2bf(v1.x);  As[r0 + 5][k] = f2bf(v1.y);
        As[r0 + 6][k] = f2bf(v1.z);  As[r0 + 7][k] = f2bf(v1.w);
    }
    __syncthreads();

    const int wave = threadIdx.x >> 6;
    const int lane = threadIdx.x & 63;
    const int llo  = lane & 15;          // col-in-tile / row-in-tile
    const int lhi  = lane >> 4;          // k-quad

    // A fragments: lane holds A[row=llo][k = s*32 + lhi*8 .. +8]
    short8 af[4];
    #pragma unroll
    for (int s = 0; s < 4; s++)
        af[s] = *(const short8*)&As[llo][s * 32 + lhi * 8];

    // B: cbb[p][col][k], k contiguous -> direct 16B global loads
    const short* bptr = cbb + ((size_t)(p * K_ + wave * 512 + llo) * D_ + lhi * 8);

    f32x4 acc[32];
    #pragma unroll
    for (int ct = 0; ct < 32; ct++) {
        const short* bp = bptr + (size_t)ct * 16 * D_;
        short8 b0 = *(const short8*)(bp +  0);
        short8 b1 = *(const short8*)(bp + 32);
        short8 b2 = *(const short8*)(bp + 64);
        short8 b3 = *(const short8*)(bp + 96);
        f32x4 a = {0.f, 0.f, 0.f, 0.f};
        a = __builtin_amdgcn_mfma_f32_16x16x32_bf16(af[0], b0, a, 0, 0, 0);
        a = __builtin_amdgcn_mfma_f32_16x16x32_bf16(af[1], b1, a, 0, 0, 0);
        a = __builtin_amdgcn_mfma_f32_16x16x32_bf16(af[2], b2, a, 0, 0, 0);
        a = __builtin_amdgcn_mfma_f32_16x16x32_bf16(af[3], b3, a, 0, 0, 0);
        acc[ct] = a;
    }

    // --- epilogue: exp (no max-sub needed: logits tiny), row sum, argmax ---
    // C layout: col = lane&15, row = (lane>>4)*4 + reg
    float rs[4] = {0.f, 0.f, 0.f, 0.f};
    float mx[4] = {-1e30f, -1e30f, -1e30f, -1e30f};
    int   mi[4] = {0, 0, 0, 0};
    const float* cn = cnorm + p * K_ + wave * 512 + llo;
    #pragma unroll
    for (int ct = 0; ct < 32; ct++) {
        float c = cn[ct * 16];
        #pragma unroll
        for (int r = 0; r < 4; r++) {
            float s = 4.0f * acc[ct][r] - 2.0f * c;
            float e = __expf(s);
            acc[ct][r] = e;
            rs[r] += e;
            if (e > mx[r]) { mx[r] = e; mi[r] = wave * 512 + ct * 16 + llo; }
        }
    }
    // reduce across the 16 lanes holding one row's columns
    #pragma unroll
    for (int m = 1; m < 16; m <<= 1) {
        #pragma unroll
        for (int r = 0; r < 4; r++) {
            rs[r] += __shfl_xor(rs[r], m, 64);
            float om = __shfl_xor(mx[r], m, 64);
            int   oi = __shfl_xor(mi[r], m, 64);
            if (om > mx[r] || (om == mx[r] && oi < mi[r])) { mx[r] = om; mi[r] = oi; }
        }
    }
    if (llo == 0) {
        #pragma unroll
        for (int r = 0; r < 4; r++) {
            int row = lhi * 4 + r;
            wsum[wave][row]  = rs[r];
            wmax[wave][row]  = mx[r];
            wmidx[wave][row] = mi[r];
        }
    }
    __syncthreads();

    float inv[4];
    #pragma unroll
    for (int r = 0; r < 4; r++) {
        int row = lhi * 4 + r;
        inv[r] = 1.0f / (wsum[0][row] + wsum[1][row] + wsum[2][row] + wsum[3][row]);
    }
    if (threadIdx.x < 16) {
        int row = threadIdx.x;
        float m0 = wmax[0][row]; int i0 = wmidx[0][row];
        #pragma unroll
        for (int w2 = 1; w2 < 4; w2++) {
            float mm = wmax[w2][row]; int ii = wmidx[w2][row];
            if (mm > m0 || (mm == m0 && ii < i0)) { m0 = mm; i0 = ii; }
        }
        idx_out[p * N_ + n0 + row] = i0;
    }

    // --- normalize + store probs ---
    float* obase = out2 + (size_t)(n0 + lhi * 4) * (P_ * K_) + p * K_ + wave * 512 + llo;
    #pragma unroll
    for (int ct = 0; ct < 32; ct++) {
        #pragma unroll
        for (int r = 0; r < 4; r++) {
            obase[(size_t)r * (P_ * K_) + ct * 16] = acc[ct][r] * inv[r];
        }
    }
}

// ---------------- gather zq + q_loss ----------------
__global__ __launch_bounds__(256) void vq_gather(const float* __restrict__ z,
                                                 const float* __restrict__ cb,
                                                 const int*   __restrict__ idx,
                                                 float* __restrict__ out0,
                                                 float* __restrict__ qloss) {
    const int bp  = blockIdx.x;          // 0..63
    const int b   = bp >> 2;
    const int p   = bp & 3;
    const int dd0 = blockIdx.y * 8;
    const int t   = threadIdx.x;
    float loss = 0.f;
    for (int hw = t; hw < HW_; hw += 256) {
        int iv = idx[p * N_ + b * HW_ + hw];
        const float* crow = cb + ((size_t)(p * K_ + iv)) * D_ + dd0;
        float4 c0 = *(const float4*)crow;
        float4 c1 = *(const float4*)(crow + 4);
        float cv[8] = {c0.x, c0.y, c0.z, c0.w, c1.x, c1.y, c1.z, c1.w};
        size_t zoff = ((size_t)b * C_ + p * D_ + dd0) * HW_ + hw;
        #pragma unroll
        for (int j = 0; j < 8; j++) {
            float zv = z[zoff + (size_t)j * HW_];
            out0[zoff + (size_t)j * HW_] = cv[j];
            float dlt = cv[j] - zv;
            loss += dlt * dlt;
        }
    }
    #pragma unroll
    for (int m = 1; m < 64; m <<= 1) loss += __shfl_xor(loss, m, 64);
    __shared__ float ls[4];
    int wave = t >> 6, lane = t & 63;
    if (lane == 0) ls[wave] = loss;
    __syncthreads();
    if (t == 0) {
        float tot = ls[0] + ls[1] + ls[2] + ls[3];
        // q_loss = (1 + BETA) * mean((zq - zf)^2), BETA = 0.25
        atomicAdd(qloss, tot * (1.25f / (float)(P_ * (size_t)N_ * D_)));
    }
}

extern "C" void kernel_launch(void* const* d_in, const int* in_sizes, int n_in,
                              void* d_out, int out_size, void* d_ws, size_t ws_size,
                              hipStream_t stream) {
    const float* z  = (const float*)d_in[0];
    const float* cb = (const float*)d_in[1];
    float* out = (float*)d_out;

    int*   ws_idx   = (int*)d_ws;                              // 200,704 B
    float* ws_cnorm = (float*)((char*)d_ws + (256 << 10));     //  32 KB
    short* ws_cbb   = (short*)((char*)d_ws + (512 << 10));     //   2 MB

    vq_prep<<<(P_ * K_) / 4, 256, 0, stream>>>(cb, ws_cbb, ws_cnorm);
    vq_main<<<P_ * (N_ / 16), 256, 0, stream>>>(z, ws_cbb, ws_cnorm, ws_idx,
                                                out + OUT2_OFF);
    hipMemsetAsync(out + QLOSS_OFF, 0, sizeof(float), stream);
    vq_gather<<<dim3(64, 16), 256, 0, stream>>>(z, cb, ws_idx, out,
                                                out + QLOSS_OFF);
}

// Round 2
// 672.043 us; speedup vs baseline: 1.0874x; 1.0874x over previous
//
#include <hip/hip_runtime.h>

#define P_    4
#define K_    2048
#define D_    128
#define B_    16
#define HW_   784
#define N_    (B_ * HW_)          // 12544
#define C_    512

#define OUT0_SZ   (B_ * C_ * HW_) // 6422528
#define QLOSS_OFF OUT0_SZ
#define OUT2_OFF  (OUT0_SZ + 1)

typedef short  short8 __attribute__((ext_vector_type(8)));
typedef float  f32x4  __attribute__((ext_vector_type(4)));

__device__ __forceinline__ short f2bf(float x) {
    union { float f; unsigned u; } a; a.f = x;
    unsigned r = a.u + 0x7FFF + ((a.u >> 16) & 1);   // RNE
    return (short)(r >> 16);
}

// ---------------- prep: codebook -> bf16 + squared norms ----------------
__global__ __launch_bounds__(256) void vq_prep(const float* __restrict__ cb,
                                               short* __restrict__ cbb,
                                               float* __restrict__ cnorm) {
    int wave = threadIdx.x >> 6;
    int lane = threadIdx.x & 63;
    int row  = blockIdx.x * 4 + wave;            // 0 .. P_*K_-1
    const float* src = cb + (size_t)row * D_;
    float2 v = *(const float2*)(src + lane * 2);
    cbb[(size_t)row * D_ + lane * 2 + 0] = f2bf(v.x);
    cbb[(size_t)row * D_ + lane * 2 + 1] = f2bf(v.y);
    float s = v.x * v.x + v.y * v.y;
    #pragma unroll
    for (int m = 1; m < 64; m <<= 1) s += __shfl_xor(s, m, 64);
    if (lane == 0) cnorm[row] = s;
}

// ---------------- main: GEMM + fused softmax/argmax ----------------
// block = 512 thr (8 waves), one p, 16 n-rows, full K=2048 cols.
// wave w owns cols [w*256, w*256+256) -> acc[16] (64 VGPR), 4 waves/SIMD.
__global__ __launch_bounds__(512, 4) void vq_main(const float* __restrict__ z,
                                                  const short* __restrict__ cbb,
                                                  const float* __restrict__ cnorm,
                                                  int*   __restrict__ idx_out,
                                                  float* __restrict__ out2) {
    __shared__ short As[16][136];        // [n-row][k], +8 pad
    __shared__ float wsum[8][16];
    __shared__ float wmax[8][16];
    __shared__ int   wmidx[8][16];

    const int bx  = blockIdx.x;
    const int p   = bx / (N_ / 16);      // 784 tiles per p (same-p blocks adjacent -> L2 reuse)
    const int nt  = bx % (N_ / 16);
    const int b   = nt / 49;             // HW_=784 = 49*16, tiles never cross b
    const int hw0 = (nt % 49) * 16;
    const int n0  = nt * 16;

    // --- stage A tile (16 rows x 128 k) as bf16, transposed, in LDS ---
    {
        int t  = threadIdx.x;            // 512 threads: k = t>>2, quarter = t&3
        int k  = t >> 2;
        int q4 = t & 3;
        const float* src = z + ((size_t)b * C_ + p * D_ + k) * HW_ + hw0 + q4 * 4;
        float4 v = *(const float4*)src;
        int r0 = q4 * 4;
        As[r0 + 0][k] = f2bf(v.x);  As[r0 + 1][k] = f2bf(v.y);
        As[r0 + 2][k] = f2bf(v.z);  As[r0 + 3][k] = f2bf(v.w);
    }
    __syncthreads();

    const int wave = threadIdx.x >> 6;
    const int lane = threadIdx.x & 63;
    const int llo  = lane & 15;          // col-in-tile / row-in-tile
    const int lhi  = lane >> 4;          // k-quad

    // A fragments: lane holds A[row=llo][k = s*32 + lhi*8 .. +8]
    short8 af[4];
    #pragma unroll
    for (int s = 0; s < 4; s++)
        af[s] = *(const short8*)&As[llo][s * 32 + lhi * 8];

    // B: cbb[p][col][k], k contiguous -> direct 16B global loads (L2-resident)
    const short* bptr = cbb + ((size_t)(p * K_ + wave * 256 + llo) * D_ + lhi * 8);

    f32x4 acc[16];
    #pragma unroll
    for (int ct = 0; ct < 16; ct++) {
        const short* bp = bptr + (size_t)ct * 16 * D_;
        short8 b0 = *(const short8*)(bp +  0);
        short8 b1 = *(const short8*)(bp + 32);
        short8 b2 = *(const short8*)(bp + 64);
        short8 b3 = *(const short8*)(bp + 96);
        f32x4 a = {0.f, 0.f, 0.f, 0.f};
        a = __builtin_amdgcn_mfma_f32_16x16x32_bf16(af[0], b0, a, 0, 0, 0);
        a = __builtin_amdgcn_mfma_f32_16x16x32_bf16(af[1], b1, a, 0, 0, 0);
        a = __builtin_amdgcn_mfma_f32_16x16x32_bf16(af[2], b2, a, 0, 0, 0);
        a = __builtin_amdgcn_mfma_f32_16x16x32_bf16(af[3], b3, a, 0, 0, 0);
        acc[ct] = a;
    }

    // --- epilogue: exp (logits tiny: no max-sub), row sum, argmax ---
    // C layout: col = lane&15, row = (lane>>4)*4 + reg
    float rs[4] = {0.f, 0.f, 0.f, 0.f};
    float mx[4] = {-1e30f, -1e30f, -1e30f, -1e30f};
    int   mi[4] = {0, 0, 0, 0};
    const float* cn = cnorm + p * K_ + wave * 256 + llo;
    #pragma unroll
    for (int ct = 0; ct < 16; ct++) {
        float c = cn[ct * 16];
        #pragma unroll
        for (int r = 0; r < 4; r++) {
            float s = 4.0f * acc[ct][r] - 2.0f * c;
            float e = __expf(s);
            acc[ct][r] = e;
            rs[r] += e;
            if (e > mx[r]) { mx[r] = e; mi[r] = wave * 256 + ct * 16 + llo; }
        }
    }
    // reduce across the 16 lanes holding one row's columns
    #pragma unroll
    for (int m = 1; m < 16; m <<= 1) {
        #pragma unroll
        for (int r = 0; r < 4; r++) {
            rs[r] += __shfl_xor(rs[r], m, 64);
            float om = __shfl_xor(mx[r], m, 64);
            int   oi = __shfl_xor(mi[r], m, 64);
            if (om > mx[r] || (om == mx[r] && oi < mi[r])) { mx[r] = om; mi[r] = oi; }
        }
    }
    if (llo == 0) {
        #pragma unroll
        for (int r = 0; r < 4; r++) {
            int row = lhi * 4 + r;
            wsum[wave][row]  = rs[r];
            wmax[wave][row]  = mx[r];
            wmidx[wave][row] = mi[r];
        }
    }
    __syncthreads();

    float inv[4];
    #pragma unroll
    for (int r = 0; r < 4; r++) {
        int row = lhi * 4 + r;
        float s = 0.f;
        #pragma unroll
        for (int w2 = 0; w2 < 8; w2++) s += wsum[w2][row];
        inv[r] = 1.0f / s;
    }
    if (threadIdx.x < 16) {
        int row = threadIdx.x;
        float m0 = wmax[0][row]; int i0 = wmidx[0][row];
        #pragma unroll
        for (int w2 = 1; w2 < 8; w2++) {
            float mm = wmax[w2][row]; int ii = wmidx[w2][row];
            if (mm > m0 || (mm == m0 && ii < i0)) { m0 = mm; i0 = ii; }
        }
        idx_out[p * N_ + n0 + row] = i0;
    }

    // --- normalize + store probs ---
    float* obase = out2 + (size_t)(n0 + lhi * 4) * (P_ * K_) + p * K_ + wave * 256 + llo;
    #pragma unroll
    for (int ct = 0; ct < 16; ct++) {
        #pragma unroll
        for (int r = 0; r < 4; r++) {
            obase[(size_t)r * (P_ * K_) + ct * 16] = acc[ct][r] * inv[r];
        }
    }
}

// ---------------- gather zq + q_loss ----------------
__global__ __launch_bounds__(256) void vq_gather(const float* __restrict__ z,
                                                 const float* __restrict__ cb,
                                                 const int*   __restrict__ idx,
                                                 float* __restrict__ out0,
                                                 float* __restrict__ qloss) {
    const int bp  = blockIdx.x;          // 0..63
    const int b   = bp >> 2;
    const int p   = bp & 3;
    const int dd0 = blockIdx.y * 8;
    const int t   = threadIdx.x;
    float loss = 0.f;
    for (int hw = t; hw < HW_; hw += 256) {
        int iv = idx[p * N_ + b * HW_ + hw];
        const float* crow = cb + ((size_t)(p * K_ + iv)) * D_ + dd0;
        float4 c0 = *(const float4*)crow;
        float4 c1 = *(const float4*)(crow + 4);
        float cv[8] = {c0.x, c0.y, c0.z, c0.w, c1.x, c1.y, c1.z, c1.w};
        size_t zoff = ((size_t)b * C_ + p * D_ + dd0) * HW_ + hw;
        #pragma unroll
        for (int j = 0; j < 8; j++) {
            float zv = z[zoff + (size_t)j * HW_];
            out0[zoff + (size_t)j * HW_] = cv[j];
            float dlt = cv[j] - zv;
            loss += dlt * dlt;
        }
    }
    #pragma unroll
    for (int m = 1; m < 64; m <<= 1) loss += __shfl_xor(loss, m, 64);
    __shared__ float ls[4];
    int wave = t >> 6, lane = t & 63;
    if (lane == 0) ls[wave] = loss;
    __syncthreads();
    if (t == 0) {
        float tot = ls[0] + ls[1] + ls[2] + ls[3];
        // q_loss = (1 + BETA) * mean((zq - zf)^2), BETA = 0.25
        atomicAdd(qloss, tot * (1.25f / (float)(P_ * (size_t)N_ * D_)));
    }
}

extern "C" void kernel_launch(void* const* d_in, const int* in_sizes, int n_in,
                              void* d_out, int out_size, void* d_ws, size_t ws_size,
                              hipStream_t stream) {
    const float* z  = (const float*)d_in[0];
    const float* cb = (const float*)d_in[1];
    float* out = (float*)d_out;

    int*   ws_idx   = (int*)d_ws;                              // 200,704 B
    float* ws_cnorm = (float*)((char*)d_ws + (256 << 10));     //  32 KB
    short* ws_cbb   = (short*)((char*)d_ws + (512 << 10));     //   2 MB

    vq_prep<<<(P_ * K_) / 4, 256, 0, stream>>>(cb, ws_cbb, ws_cnorm);
    vq_main<<<P_ * (N_ / 16), 512, 0, stream>>>(z, ws_cbb, ws_cnorm, ws_idx,
                                                out + OUT2_OFF);
    hipMemsetAsync(out + QLOSS_OFF, 0, sizeof(float), stream);
    vq_gather<<<dim3(64, 16), 256, 0, stream>>>(z, cb, ws_idx, out,
                                                out + QLOSS_OFF);
}